// Round 1
// baseline (13875.092 us; speedup 1.0000x reference)
//
#include <hip/hip_runtime.h>
#include <cstddef>

// Problem constants (from reference setup_inputs)
#define S_ 512
#define B_ 64
#define I_ 256
#define H_ 1024

// ---------------------------------------------------------------------------
// Transpose: out[c*R + r] = in[r*C + c].  R,C multiples of 32.
// block = 256 threads (32x8 logical), grid = (C/32, R/32)
// ---------------------------------------------------------------------------
__global__ __launch_bounds__(256) void transpose_k(const float* __restrict__ in,
                                                   float* __restrict__ out,
                                                   int R, int C) {
  __shared__ float t[32][33];  // +1 pad: no bank conflicts on transposed read
  int c0 = blockIdx.x * 32, r0 = blockIdx.y * 32;
  int x = threadIdx.x & 31, y = threadIdx.x >> 5;  // 32x8
  for (int i = 0; i < 32; i += 8) {
    t[y + i][x] = in[(size_t)(r0 + y + i) * C + (c0 + x)];
  }
  __syncthreads();
  for (int i = 0; i < 32; i += 8) {
    out[(size_t)(c0 + y + i) * R + (r0 + x)] = t[x][y + i];
  }
}

// ---------------------------------------------------------------------------
// xproj: out[m*H + j] = dot(x[m, 0:256], WxT[:, j]) + bx[j]
// block = 256 threads (one j-column each), handles 4 m-rows -> 4 outputs/thread
// grid = (H/256=4, S*B/4=8192)
// ---------------------------------------------------------------------------
__global__ __launch_bounds__(256) void xproj_kernel(const float* __restrict__ x,
                                                    const float* __restrict__ WxT,
                                                    const float* __restrict__ bx,
                                                    float* __restrict__ out) {
  __shared__ float xs[4][I_];
  int tid = threadIdx.x;
  int j = blockIdx.x * 256 + tid;
  size_t m0 = (size_t)blockIdx.y * 4;
  const float* xrow = x + m0 * I_;
  // stage 4 rows of x (4 x 256 floats), coalesced
  for (int r = 0; r < 4; ++r) xs[r][tid] = xrow[(size_t)r * I_ + tid];
  __syncthreads();

  float bj = bx[j];
  float a0 = bj, a1 = bj, a2 = bj, a3 = bj;
  const float* wp = WxT + j;
  for (int k = 0; k < I_; k += 4) {
    float w0 = wp[(size_t)(k + 0) * H_];
    float w1 = wp[(size_t)(k + 1) * H_];
    float w2 = wp[(size_t)(k + 2) * H_];
    float w3 = wp[(size_t)(k + 3) * H_];
    float4 v0 = *(const float4*)&xs[0][k];
    float4 v1 = *(const float4*)&xs[1][k];
    float4 v2 = *(const float4*)&xs[2][k];
    float4 v3 = *(const float4*)&xs[3][k];
    a0 += w0 * v0.x + w1 * v0.y + w2 * v0.z + w3 * v0.w;
    a1 += w0 * v1.x + w1 * v1.y + w2 * v1.z + w3 * v1.w;
    a2 += w0 * v2.x + w1 * v2.y + w2 * v2.z + w3 * v2.w;
    a3 += w0 * v3.x + w1 * v3.y + w2 * v3.z + w3 * v3.w;
  }
  out[(m0 + 0) * H_ + j] = a0;
  out[(m0 + 1) * H_ + j] = a1;
  out[(m0 + 2) * H_ + j] = a2;
  out[(m0 + 3) * H_ + j] = a3;
}

// ---------------------------------------------------------------------------
// One recurrence step: out[t] = tanh(WhT^T-dot(h_prev) + bh + xproj_t)
// h state lives IN d_out: slot t holds xproj_t before this kernel, h_t after.
// grid = (16 j-tiles of 64, 16 b-tiles of 4), block = 256 (4 waves).
// wave = 64 lanes along j -> WhT reads coalesced 256B; hs read is same-address
// broadcast across the wave (free).
// ---------------------------------------------------------------------------
__global__ __launch_bounds__(256) void rnn_step(const float* __restrict__ WhT,
                                                const float* __restrict__ bh,
                                                float* __restrict__ out,
                                                int t, int first,
                                                float* __restrict__ out_last) {
  __shared__ float hs[4][H_];
  int tid = threadIdx.x;
  int lane = tid & 63, bl = tid >> 6;
  int j = blockIdx.x * 64 + lane;
  int b = blockIdx.y * 4 + bl;

  float acc = 0.f;
  if (!first) {
    // stage h_{t-1} rows [4*blockIdx.y, +4) : 4096 floats = 1024 float4
    const float4* hp4 =
        (const float4*)(out + (size_t)(t - 1) * B_ * H_ + (size_t)blockIdx.y * 4 * H_);
    float4* hs4 = (float4*)&hs[0][0];
    for (int i = tid; i < H_; i += 256) hs4[i] = hp4[i];
    __syncthreads();

    const float* wp = WhT + j;
    #pragma unroll 2
    for (int k = 0; k < H_; k += 4) {
      float w0 = wp[(size_t)(k + 0) * H_];
      float w1 = wp[(size_t)(k + 1) * H_];
      float w2 = wp[(size_t)(k + 2) * H_];
      float w3 = wp[(size_t)(k + 3) * H_];
      float4 hv = *(const float4*)&hs[bl][k];
      acc += w0 * hv.x + w1 * hv.y + w2 * hv.z + w3 * hv.w;
    }
  }

  size_t idx = (size_t)b * H_ + j;
  float z = acc + bh[j] + out[(size_t)t * B_ * H_ + idx];  // xproj_t read in place
  float h = tanhf(z);
  out[(size_t)t * B_ * H_ + idx] = h;
  if (out_last) out_last[idx] = h;
}

// ---------------------------------------------------------------------------
// Launch. ws layout: WhT (1024*1024 f32 = 4MB) | WxT (256*1024 f32 = 1MB)
// Requires ws_size >= 5 MiB.
// ---------------------------------------------------------------------------
extern "C" void kernel_launch(void* const* d_in, const int* in_sizes, int n_in,
                              void* d_out, int out_size, void* d_ws, size_t ws_size,
                              hipStream_t stream) {
  const float* x  = (const float*)d_in[0];
  const float* Wx = (const float*)d_in[1];
  const float* bx = (const float*)d_in[2];
  const float* Wh = (const float*)d_in[3];
  const float* bh = (const float*)d_in[4];
  float* out = (float*)d_out;
  float* WhT = (float*)d_ws;                  // [H_][H_] : WhT[k][j] = Wh[j][k]
  float* WxT = WhT + (size_t)H_ * H_;         // [I_][H_] : WxT[k][j] = Wx[j][k]

  hipLaunchKernelGGL(transpose_k, dim3(H_ / 32, H_ / 32), dim3(256), 0, stream,
                     Wh, WhT, H_, H_);
  hipLaunchKernelGGL(transpose_k, dim3(I_ / 32, H_ / 32), dim3(256), 0, stream,
                     Wx, WxT, H_, I_);
  hipLaunchKernelGGL(xproj_kernel, dim3(H_ / 256, (S_ * B_) / 4), dim3(256), 0, stream,
                     x, WxT, bx, out);
  for (int t = 0; t < S_; ++t) {
    float* out_last = (t == S_ - 1) ? out + (size_t)S_ * B_ * H_ : nullptr;
    hipLaunchKernelGGL(rnn_step, dim3(16, 16), dim3(256), 0, stream,
                       WhT, bh, out, t, (t == 0) ? 1 : 0, out_last);
  }
}